// Round 4
// baseline (701.964 us; speedup 1.0000x reference)
//
#include <hip/hip_runtime.h>
#include <stdint.h>
#include <stddef.h>

typedef __bf16 bf16;
typedef __attribute__((ext_vector_type(8))) __bf16 bf16x8;
typedef __attribute__((ext_vector_type(4))) __bf16 bf16x4;
typedef __attribute__((ext_vector_type(4))) float f32x4;

#define ATT_EPS 1e-6f

// async global->LDS, 16B per lane; LDS dest = wave-uniform base + lane*16
__device__ __forceinline__ void lds16(const void* g, void* l) {
    __builtin_amdgcn_global_load_lds(
        (const __attribute__((address_space(1))) void*)g,
        (__attribute__((address_space(3))) void*)l, 16, 0, 0);
}

// ---------------------------------------------------------------------------
__global__ __launch_bounds__(256) void cvt_bf16(const float4* __restrict__ in,
                                                bf16x4* __restrict__ out, int n4) {
    int i = blockIdx.x * 256 + threadIdx.x;
    if (i < n4) {
        float4 v = in[i];
        bf16x4 o;
        o.x = (bf16)v.x; o.y = (bf16)v.y; o.z = (bf16)v.z; o.w = (bf16)v.w;
        out[i] = o;
    }
}

// ---------------------------------------------------------------------------
__global__ __launch_bounds__(256) void transpose_w(const float* __restrict__ W,
                                                   bf16* __restrict__ Wt) {
    __shared__ float tile[32][33];
    const int bx = blockIdx.x * 32, by = blockIdx.y * 32;
    const int tx = threadIdx.x, ty = threadIdx.y; // 32 x 8
#pragma unroll
    for (int j = 0; j < 32; j += 8)
        tile[ty + j][tx] = W[(size_t)(by + ty + j) * 1024 + bx + tx];
    __syncthreads();
#pragma unroll
    for (int j = 0; j < 32; j += 8)
        Wt[(size_t)(bx + ty + j) * 1024 + by + tx] = (bf16)tile[tx][ty + j];
}

// ---------------------------------------------------------------------------
// 256x128 tile GEMM, C[m][n] = sum_k A[m][k]*B[n][k]. 8 waves (4M x 2N),
// per-wave 64x64 (acc = 64 VGPR), BK=32, NT = K/32 (even, >= 6).
// 4-stage circular LDS buffer (4 x 24KB = 96KB). Fragment DOUBLE-BUFFERING:
// phase tt issues ds_reads for tile tt+1 (bank p^1) wait-free right after the
// barrier, then MFMAs tile tt (bank p, drained by this phase's lgkmcnt(0)).
// LDS pipe overlaps MFMA pipe. One barrier per phase.
// Sync proofs:
//   WAR: STAGE(tt+3) -> buf (tt-1)&3; its last reads (frags(tt-1), issued
//        phase tt-2) are drained by every wave's lgkmcnt(0) BEFORE
//        barrier(tt-1); STAGE issues after that barrier.
//   RAW: vmcnt(6) at phase tt retires each wave's 3 oldest stages =
//        tile tt+1; barrier => all waves' slices resident before reads.
// st_16x32 swizzle via pre-swizzled global SOURCE + swizzled ds_read offset
// (involution on byte-bit-5 keyed by byte-bit-9).
// MODE: 0 = fp32 direct store, 1 = bf16 via LDS repack, 2 = phi + bf16.
// ---------------------------------------------------------------------------
template <int MODE>
__global__ __launch_bounds__(512) void gemm_px(const bf16* __restrict__ A, int lda,
                                               const bf16* __restrict__ B, int ldb,
                                               void* __restrict__ C, int ldc,
                                               int K, int fast_m, int fl2) {
    __shared__ bf16 smem[49152] __attribute__((aligned(16))); // 96 KiB
    const int t = threadIdx.x;
    const int wave = t >> 6, lane = t & 63;
    // bijective XCD-chunked swizzle (gridDim.x % 8 == 0)
    const int q8 = gridDim.x >> 3;
    const int wg = (blockIdx.x & 7) * q8 + (blockIdx.x >> 3);
    const int f = wg & ((1 << fl2) - 1), s = wg >> fl2;
    const int mt = fast_m ? f : s, nt = fast_m ? s : f;
    const int tileM = mt << 8, tileN = nt << 7;
    const int wm = wave >> 1, wn = wave & 1; // 4 x 2 wave grid

    // staging coords: LDS linear byte -> (row, col) of swizzled layout
    // ([16 rows][32 cols] bf16 subtiles of 1024B, byte ^= ((byte>>9)&1)<<5)
    int rA[2], cA[2], rB, cB;
#pragma unroll
    for (int j = 0; j < 2; j++) {
        int ol = t * 16 + j * 8192;
        int o = ol & 1023, op = o ^ (((o >> 9) & 1) << 5);
        rA[j] = ((ol >> 10) << 4) | (op >> 6);
        cA[j] = (op & 63) >> 1;
    }
    {
        int ol = t * 16;
        int o = ol & 1023, op = o ^ (((o >> 9) & 1) << 5);
        rB = ((ol >> 10) << 4) | (op >> 6);
        cB = (op & 63) >> 1;
    }
    const bf16* gA0 = A + (size_t)(tileM + rA[0]) * lda + cA[0];
    const bf16* gA1 = A + (size_t)(tileM + rA[1]) * lda + cA[1];
    const bf16* gB0 = B + (size_t)(tileN + rB) * ldb + cB;

    const int rm = lane & 15, qq = lane >> 4;
    const int foffE = ((rm * 64 + qq * 16) ^ ((rm >> 3) << 5)) >> 1;

    f32x4 acc[4][4] = {};
    bf16x8 af0[4], bv0[4], af1[4], bv1[4];

#define STAGE(tt)                                                              \
    {                                                                          \
        bf16* b_ = smem + ((tt) & 3) * 12288;                                  \
        const int k_ = (tt) << 5;                                              \
        lds16(gA0 + k_, b_ + wave * 512);                                      \
        lds16(gA1 + k_, b_ + 4096 + wave * 512);                               \
        lds16(gB0 + k_, b_ + 8192 + wave * 512);                               \
    }

#define PHASE(tt, afR, bvR, afW, bvW, DOSTG, VM, DORD)                         \
    {                                                                          \
        if (DOSTG) STAGE((tt) + 3);                                            \
        asm volatile("s_waitcnt vmcnt(" #VM ")" ::: "memory");                 \
        asm volatile("s_waitcnt lgkmcnt(0)" ::: "memory");                     \
        asm volatile("s_barrier" ::: "memory");                                \
        if (DORD) {                                                            \
            const bf16* pA_ =                                                  \
                smem + (((tt) + 1) & 3) * 12288 + wm * 2048 + foffE;           \
            const bf16* pB_ =                                                  \
                smem + (((tt) + 1) & 3) * 12288 + 8192 + wn * 2048 + foffE;    \
            _Pragma("unroll") for (int mi = 0; mi < 4; mi++)                   \
                afW[mi] = *(const bf16x8*)(pA_ + mi * 512);                    \
            _Pragma("unroll") for (int ni = 0; ni < 4; ni++)                   \
                bvW[ni] = *(const bf16x8*)(pB_ + ni * 512);                    \
        }                                                                      \
        __builtin_amdgcn_s_setprio(1);                                         \
        _Pragma("unroll") for (int mi = 0; mi < 4; mi++)                       \
            _Pragma("unroll") for (int ni = 0; ni < 4; ni++)                   \
                acc[mi][ni] = __builtin_amdgcn_mfma_f32_16x16x32_bf16(         \
                    afR[mi], bvR[ni], acc[mi][ni], 0, 0, 0);                   \
        __builtin_amdgcn_s_setprio(0);                                         \
    }

    const int NT = K >> 5; // even, >= 6 (K=1024 -> 32)
    STAGE(0); STAGE(1); STAGE(2);
    asm volatile("s_waitcnt vmcnt(6)" ::: "memory"); // tile 0 resident
    asm volatile("s_barrier" ::: "memory");
    {
        const bf16* pA_ = smem + wm * 2048 + foffE;
        const bf16* pB_ = smem + 8192 + wn * 2048 + foffE;
#pragma unroll
        for (int mi = 0; mi < 4; mi++) af0[mi] = *(const bf16x8*)(pA_ + mi * 512);
#pragma unroll
        for (int ni = 0; ni < 4; ni++) bv0[ni] = *(const bf16x8*)(pB_ + ni * 512);
    }
    for (int tt = 0; tt < NT - 4; tt += 2) {
        PHASE(tt,     af0, bv0, af1, bv1, 1, 6, 1);
        PHASE(tt + 1, af1, bv1, af0, bv0, 1, 6, 1);
    }
    PHASE(NT - 4, af0, bv0, af1, bv1, 1, 6, 1);
    PHASE(NT - 3, af1, bv1, af0, bv0, 0, 3, 1);
    PHASE(NT - 2, af0, bv0, af1, bv1, 0, 0, 1);
    PHASE(NT - 1, af1, bv1, af0, bv0, 0, 0, 0);
#undef STAGE
#undef PHASE

    const int row0 = (lane >> 4) * 4, col = lane & 15;
    if (MODE == 0) {
        float* Cf = (float*)C;
#pragma unroll
        for (int mi = 0; mi < 4; mi++)
#pragma unroll
            for (int ni = 0; ni < 4; ni++)
#pragma unroll
                for (int r = 0; r < 4; r++) {
                    int gm = tileM + wm * 64 + mi * 16 + row0 + r;
                    int gn = tileN + wn * 64 + ni * 16 + col;
                    Cf[(size_t)gm * ldc + gn] = acc[mi][ni][r];
                }
    } else {
        // repack 256x128 bf16 tile (stride 128, 64KB, bufs 0-2: no overlap
        // with buf 3 = the only buffer with possibly-pending reads)
        bf16* Cb = (bf16*)C;
#pragma unroll
        for (int mi = 0; mi < 4; mi++)
#pragma unroll
            for (int ni = 0; ni < 4; ni++)
#pragma unroll
                for (int r = 0; r < 4; r++) {
                    float v = acc[mi][ni][r];
                    if (MODE == 2) v = (v > 0.f) ? (v + 1.f) : __expf(v);
                    smem[(wm * 64 + mi * 16 + row0 + r) * 128 +
                         wn * 64 + ni * 16 + col] = (bf16)v;
                }
        __syncthreads();
#pragma unroll
        for (int i = 0; i < 8; i++) {
            int c = t + i * 512;
            int row = c >> 4, cb = (c & 15) * 8;
            *(bf16x8*)&Cb[(size_t)(tileM + row) * ldc + tileN + cb] =
                *(const bf16x8*)&smem[row * 128 + cb];
        }
    }
}

// ---------------------------------------------------------------------------
// Phase 2: per (b,h): KvT[n][m] += sum_l Kf[l][m] V[l][n];  row 64 = K1
// ---------------------------------------------------------------------------
__global__ __launch_bounds__(256) void kv_reduce(const bf16* __restrict__ Kft,
                                                 const bf16* __restrict__ Vt,
                                                 float* __restrict__ Kv) {
    const int chunk = blockIdx.x; // 0..7
    const int bh = blockIdx.y;    // 0..63
    const int b = bh >> 4, h = bh & 15;
    __shared__ bf16 sA[64 * 32] __attribute__((aligned(16)));
    __shared__ bf16 sB[64 * 32] __attribute__((aligned(16)));
    const int t = threadIdx.x, wave = t >> 6, lane = t & 63;
    const size_t cbase = (size_t)b * 8192 + (size_t)chunk * 1024;
    const int srow = t >> 2, scol = (t & 3) * 8;
    const bf16* a0 = Kft + (size_t)(h * 64 + srow) * 32768 + cbase + scol;
    const bf16* b0 = Vt + (size_t)(h * 64 + srow) * 32768 + cbase + scol;
    bf16* dA = sA + wave * 512;
    bf16* dB = sB + wave * 512;
    const int rm = lane & 15, qk = (lane >> 4) * 8;

    f32x4 acc[4] = {};
    f32x4 acc1 = {0.f, 0.f, 0.f, 0.f};
    bf16x8 ones;
#pragma unroll
    for (int j = 0; j < 8; j++) ones[j] = (bf16)1.0f;

    for (int k0 = 0; k0 < 1024; k0 += 32) {
        lds16(a0 + k0, dA);
        lds16(b0 + k0, dB);
        __builtin_amdgcn_s_waitcnt(0);
        __syncthreads();
        bf16x8 af = *(const bf16x8*)&sA[(wave * 16 + rm) * 32 + qk];
        bf16x8 bfr[4];
#pragma unroll
        for (int ni = 0; ni < 4; ni++)
            bfr[ni] = *(const bf16x8*)&sB[(ni * 16 + rm) * 32 + qk];
#pragma unroll
        for (int ni = 0; ni < 4; ni++)
            acc[ni] = __builtin_amdgcn_mfma_f32_16x16x32_bf16(af, bfr[ni], acc[ni], 0, 0, 0);
        acc1 = __builtin_amdgcn_mfma_f32_16x16x32_bf16(af, ones, acc1, 0, 0, 0);
        __syncthreads();
    }

    float* out = Kv + bh * 65 * 64;
    const int row0 = (lane >> 4) * 4, col = lane & 15;
    const int m0 = wave * 16 + row0;
#pragma unroll
    for (int ni = 0; ni < 4; ni++)
#pragma unroll
        for (int r = 0; r < 4; r++)
            atomicAdd(&out[(ni * 16 + col) * 64 + m0 + r], acc[ni][r]);
    if (col == 0) {
#pragma unroll
        for (int r = 0; r < 4; r++) atomicAdd(&out[64 * 64 + m0 + r], acc1[r]);
    }
}

// ---------------------------------------------------------------------------
// Phase 3: attn = num/den, LDS-repacked vector epilogue.
// ---------------------------------------------------------------------------
__global__ __launch_bounds__(256) void attn_out(const bf16* __restrict__ Qf,
                                                const float* __restrict__ Kv,
                                                bf16* __restrict__ attn) {
    const int lt = blockIdx.x; // 0..63
    const int bh = blockIdx.y; // 0..63
    const int b = bh >> 4, h = bh & 15;
    constexpr int EP_STRIDE = 80;
    __shared__ bf16 smem[13312] __attribute__((aligned(16)));
    __shared__ float den[128];
    bf16* sQ = smem;
    bf16* sB = smem + 8192;
    const int t = threadIdx.x, wave = t >> 6, lane = t & 63;
    const int qrow = t >> 3, qc = (t & 7) * 8;
    const bf16* qp = Qf + (size_t)(b * 8192 + lt * 128 + qrow) * 1024 + h * 64 + qc;
#pragma unroll
    for (int i = 0; i < 4; i++)
        lds16(qp + (size_t)i * 32 * 1024, sQ + i * 2048 + wave * 512);
    const float* kv = Kv + bh * 65 * 64;
    for (int idx = t; idx < 80 * 64; idx += 256) {
        int n = idx >> 6, k2 = idx & 63;
        sB[idx] = (n < 65) ? (bf16)kv[n * 64 + k2] : (bf16)0.f;
    }
    __builtin_amdgcn_s_waitcnt(0);
    __syncthreads();

    f32x4 acc[2][5] = {};
    const int rm = lane & 15, qk = (lane >> 4) * 8;
#pragma unroll
    for (int k0 = 0; k0 < 64; k0 += 32) {
        bf16x8 af[2], bfr[5];
#pragma unroll
        for (int mi = 0; mi < 2; mi++)
            af[mi] = *(const bf16x8*)&sQ[(wave * 32 + mi * 16 + rm) * 64 + k0 + qk];
#pragma unroll
        for (int ni = 0; ni < 5; ni++)
            bfr[ni] = *(const bf16x8*)&sB[(ni * 16 + rm) * 64 + k0 + qk];
#pragma unroll
        for (int mi = 0; mi < 2; mi++)
#pragma unroll
            for (int ni = 0; ni < 5; ni++)
                acc[mi][ni] = __builtin_amdgcn_mfma_f32_16x16x32_bf16(
                    af[mi], bfr[ni], acc[mi][ni], 0, 0, 0);
    }

    const int row0 = (lane >> 4) * 4, col = lane & 15;
    if (col == 0) {
#pragma unroll
        for (int mi = 0; mi < 2; mi++)
#pragma unroll
            for (int r = 0; r < 4; r++)
                den[wave * 32 + mi * 16 + row0 + r] = acc[mi][4][r] + ATT_EPS;
    }
    __syncthreads();
#pragma unroll
    for (int mi = 0; mi < 2; mi++)
#pragma unroll
        for (int ni = 0; ni < 4; ni++)
#pragma unroll
            for (int r = 0; r < 4; r++) {
                int rl = wave * 32 + mi * 16 + row0 + r;
                smem[rl * EP_STRIDE + ni * 16 + col] =
                    (bf16)(acc[mi][ni][r] / den[rl]);
            }
    __syncthreads();
    const int er = t >> 3, ec = (t & 7) * 8;
#pragma unroll
    for (int i = 0; i < 4; i++) {
        int row = er + i * 32;
        *(bf16x8*)&attn[(size_t)(b * 8192 + lt * 128 + row) * 1024 + h * 64 + ec] =
            *(const bf16x8*)&smem[row * EP_STRIDE + ec];
    }
}

// ---------------------------------------------------------------------------
extern "C" void kernel_launch(void* const* d_in, const int* in_sizes, int n_in,
                              void* d_out, int out_size, void* d_ws, size_t ws_size,
                              hipStream_t stream) {
    const float* x  = (const float*)d_in[0];
    const float* Wq = (const float*)d_in[1];
    const float* Wk = (const float*)d_in[2];
    const float* Wv = (const float*)d_in[3];
    const float* Wo = (const float*)d_in[4];

    char* ws = (char*)d_ws;
    bf16* xb  = (bf16*)ws;                           // 64 MB, reused as attn
    bf16* Qf  = (bf16*)(ws + ((size_t)64 << 20));    // 64 MB
    bf16* Kft = (bf16*)(ws + ((size_t)128 << 20));   // 64 MB
    bf16* Vt  = (bf16*)(ws + ((size_t)192 << 20));   // 64 MB
    bf16* Wqt = (bf16*)(ws + ((size_t)256 << 20));   // 2 MB each
    bf16* Wkt = Wqt + 1024 * 1024;
    bf16* Wvt = Wkt + 1024 * 1024;
    bf16* Wot = Wvt + 1024 * 1024;
    float* Kv = (float*)(Wot + 1024 * 1024);         // 64*65*64 fp32
    bf16* attn = xb;

    cvt_bf16<<<8388608 / 256, 256, 0, stream>>>((const float4*)x, (bf16x4*)xb, 8388608);
    dim3 tb(32, 8);
    transpose_w<<<dim3(32, 32), tb, 0, stream>>>(Wq, Wqt);
    transpose_w<<<dim3(32, 32), tb, 0, stream>>>(Wk, Wkt);
    transpose_w<<<dim3(32, 32), tb, 0, stream>>>(Wv, Wvt);
    transpose_w<<<dim3(32, 32), tb, 0, stream>>>(Wo, Wot);
    hipMemsetAsync(Kv, 0, (size_t)64 * 65 * 64 * sizeof(float), stream);

    // Qf = phi(x @ Wq): 128 m-tiles x 8 n-tiles, N fast (fl2=3)
    gemm_px<2><<<1024, 512, 0, stream>>>(xb, 1024, Wqt, 1024, Qf, 1024, 1024, 0, 3);
    // Kft = phi(Wk^T x^T): 4 m-tiles x 256 n-tiles, M fast (fl2=2)
    gemm_px<2><<<1024, 512, 0, stream>>>(Wkt, 1024, xb, 1024, Kft, 32768, 1024, 1, 2);
    // Vt = Wv^T x^T
    gemm_px<1><<<1024, 512, 0, stream>>>(Wvt, 1024, xb, 1024, Vt, 32768, 1024, 1, 2);
    // KvT (+K1 row) per (b,h), 8 l-chunks
    kv_reduce<<<dim3(8, 64), 256, 0, stream>>>(Kft, Vt, Kv);
    // attn = num/den (into xb)
    attn_out<<<dim3(64, 64), 256, 0, stream>>>(Qf, Kv, attn);
    // out = attn @ Wo (fp32), N fast
    gemm_px<0><<<1024, 512, 0, stream>>>(attn, 1024, Wot, 1024, d_out, 1024, 1024, 0, 3);
}

// Round 5
// 646.622 us; speedup vs baseline: 1.0856x; 1.0856x over previous
//
#include <hip/hip_runtime.h>
#include <stdint.h>
#include <stddef.h>

typedef __bf16 bf16;
typedef __attribute__((ext_vector_type(8))) __bf16 bf16x8;
typedef __attribute__((ext_vector_type(4))) __bf16 bf16x4;
typedef __attribute__((ext_vector_type(4))) float f32x4;

#define ATT_EPS 1e-6f

// async global->LDS, 16B per lane; LDS dest = wave-uniform base + lane*16
__device__ __forceinline__ void lds16(const void* g, void* l) {
    __builtin_amdgcn_global_load_lds(
        (const __attribute__((address_space(1))) void*)g,
        (__attribute__((address_space(3))) void*)l, 16, 0, 0);
}

// ---------------------------------------------------------------------------
__global__ __launch_bounds__(256) void cvt_bf16(const float4* __restrict__ in,
                                                bf16x4* __restrict__ out, int n4) {
    int i = blockIdx.x * 256 + threadIdx.x;
    if (i < n4) {
        float4 v = in[i];
        bf16x4 o;
        o.x = (bf16)v.x; o.y = (bf16)v.y; o.z = (bf16)v.z; o.w = (bf16)v.w;
        out[i] = o;
    }
}

// ---------------------------------------------------------------------------
__global__ __launch_bounds__(256) void transpose_w(const float* __restrict__ W,
                                                   bf16* __restrict__ Wt) {
    __shared__ float tile[32][33];
    const int bx = blockIdx.x * 32, by = blockIdx.y * 32;
    const int tx = threadIdx.x, ty = threadIdx.y; // 32 x 8
#pragma unroll
    for (int j = 0; j < 32; j += 8)
        tile[ty + j][tx] = W[(size_t)(by + ty + j) * 1024 + bx + tx];
    __syncthreads();
#pragma unroll
    for (int j = 0; j < 32; j += 8)
        Wt[(size_t)(bx + ty + j) * 1024 + by + tx] = (bf16)tile[tx][ty + j];
}

// ---------------------------------------------------------------------------
// 256x256 tile GEMM, C[m][n] = sum_k A[m][k]*B[n][k]. m201 8-phase port.
// 512 threads = 8 waves (2M x 4N), per-wave 128x64 output, BK=64.
// LDS = 8 half-tile slots of 16KB (cyclic over 2 K-tiles, 128KB):
//   slot(t, it) = (t&1)*4 + it, items: 0=A_k0, 1=B_k0, 2=A_k1, 3=B_k1,
//   each [256 rows][32 k-cols] bf16.
// Per K-tile, 4 phases: phase p (kk=p>>1, mh=p&1) =
//   { 4 A-frag ds_read_b128 (+4 B-frag when mh==0) | stage item p of K-tile
//     t+1 (2 x global_load_lds / thread) | vmcnt(4) | barrier | lgkmcnt(0) |
//     setprio(1) 16 MFMA setprio(0) | barrier }.
// vmcnt ledger (per wave, 2 loads per stage): after each phase's stage, 4
// half-tiles in flight; vmcnt(4) retires the oldest = the half consumed next
// phase. Prologue: stage K-tile 0, vmcnt(4) (items 0,1 resident). Epilogue
// tile: no stage, vmcnt 2 -> 0. Never drains to 0 in the main loop.
// WAR: slot of item p (tile t-1) is overwritten at phase p of tile t, >= 3
// phases after its last ds_read, which drained at that phase's lgkmcnt(0)
// before barrier2.
// LDS swizzle: byte bits [5:4] ^= (row>>1)&3 (involution; key folds to the
// per-lane constant (rm>>1)&3 for fragment reads). Fragment read: 16 lanes
// per qq spread over 8 bank-groups = 2-way = free (m136). Staged via
// pre-swizzled global SOURCE, linear LDS dest.
// MODE: 0 = fp32 direct store, 1 = bf16 via LDS repack, 2 = phi + bf16.
// ---------------------------------------------------------------------------
template <int MODE>
__global__ __launch_bounds__(512) void gemm8p(const bf16* __restrict__ A, int lda,
                                              const bf16* __restrict__ B, int ldb,
                                              void* __restrict__ C, int ldc,
                                              int K, int fast_m, int fl2) {
    __shared__ bf16 smem[65536] __attribute__((aligned(16))); // 128 KiB
    const int t = threadIdx.x;
    const int wave = t >> 6, lane = t & 63;
    // bijective XCD-chunked swizzle (gridDim.x % 8 == 0)
    const int q8 = gridDim.x >> 3;
    const int wg = (blockIdx.x & 7) * q8 + (blockIdx.x >> 3);
    const int f = wg & ((1 << fl2) - 1), s = wg >> fl2;
    const int mt = fast_m ? f : s, nt = fast_m ? s : f;
    const int tileM = mt << 8, tileN = nt << 8;
    const int wm = wave >> 2, wn = wave & 3; // 2 x 4 wave grid

    // staging: thread t covers bytes [t*16, t*16+16) (rows 0-127) and +8192
    // (rows 128-255) of each 16KB slot. Source col pre-swizzled.
    const int sRow = t >> 2;
    const int sc = (((t & 3) * 16) ^ (((sRow >> 1) & 3) << 4)) >> 1; // elems
    const bf16* gA0 = A + (size_t)(tileM + sRow) * lda + sc;
    const bf16* gA1 = A + (size_t)(tileM + 128 + sRow) * lda + sc;
    const bf16* gB0 = B + (size_t)(tileN + sRow) * ldb + sc;
    const bf16* gB1 = B + (size_t)(tileN + 128 + sRow) * ldb + sc;

    const int rm = lane & 15, qq = lane >> 4;
    const int cx = (qq ^ ((rm >> 1) & 3)) * 8; // swizzled 16B-slot, elems

    f32x4 acc[8][4] = {};
    bf16x8 af[4], bv[4];

#define STG(tt, it)                                                            \
    {                                                                          \
        bf16* d_ = smem + ((tt) & 1) * 32768 + (it) * 8192 + wave * 512;       \
        const int ko_ = (tt) * 64 + ((it) >> 1) * 32;                          \
        lds16((((it) & 1) ? gB0 : gA0) + ko_, d_);                             \
        lds16((((it) & 1) ? gB1 : gA1) + ko_, d_ + 4096);                      \
    }

#define PHASE(tt, p, DOSTG, VM)                                                \
    {                                                                          \
        constexpr int kk_ = (p) >> 1, mh_ = (p) & 1;                           \
        const bf16* as_ = smem + ((tt) & 1) * 32768 + kk_ * 16384;             \
        const bf16* bs_ = as_ + 8192;                                          \
        if (mh_ == 0) {                                                        \
            _Pragma("unroll") for (int ni = 0; ni < 4; ni++)                   \
                bv[ni] = *(const bf16x8*)(bs_ + (wn * 64 + ni * 16 + rm) * 32  \
                                          + cx);                               \
        }                                                                      \
        _Pragma("unroll") for (int mi = 0; mi < 4; mi++)                       \
            af[mi] = *(const bf16x8*)(as_ +                                    \
                (wm * 128 + (mh_ * 4 + mi) * 16 + rm) * 32 + cx);              \
        if (DOSTG) STG((tt) + 1, p);                                           \
        asm volatile("s_waitcnt vmcnt(" #VM ")" ::: "memory");                 \
        asm volatile("s_barrier" ::: "memory");                                \
        asm volatile("s_waitcnt lgkmcnt(0)" ::: "memory");                     \
        __builtin_amdgcn_s_setprio(1);                                         \
        _Pragma("unroll") for (int mi = 0; mi < 4; mi++)                       \
            _Pragma("unroll") for (int ni = 0; ni < 4; ni++)                   \
                acc[mh_ * 4 + mi][ni] = __builtin_amdgcn_mfma_f32_16x16x32_bf16(\
                    af[mi], bv[ni], acc[mh_ * 4 + mi][ni], 0, 0, 0);           \
        __builtin_amdgcn_s_setprio(0);                                         \
        asm volatile("s_barrier" ::: "memory");                                \
    }

    const int NKT = K >> 6; // 16 for K=1024
    STG(0, 0); STG(0, 1); STG(0, 2); STG(0, 3);
    asm volatile("s_waitcnt vmcnt(4)" ::: "memory"); // items 0,1 resident
    asm volatile("s_barrier" ::: "memory");
    for (int tt = 0; tt < NKT - 1; ++tt) {
        PHASE(tt, 0, 1, 4);
        PHASE(tt, 1, 1, 4);
        PHASE(tt, 2, 1, 4);
        PHASE(tt, 3, 1, 4);
    }
    PHASE(NKT - 1, 0, 0, 2);
    PHASE(NKT - 1, 1, 0, 0);
    PHASE(NKT - 1, 2, 0, 0);
    PHASE(NKT - 1, 3, 0, 0);
#undef STG
#undef PHASE

    const int row0 = (lane >> 4) * 4, col = lane & 15;
    if (MODE == 0) {
        float* Cf = (float*)C;
#pragma unroll
        for (int mi = 0; mi < 8; mi++)
#pragma unroll
            for (int ni = 0; ni < 4; ni++)
#pragma unroll
                for (int r = 0; r < 4; r++) {
                    int gm = tileM + wm * 128 + mi * 16 + row0 + r;
                    int gn = tileN + wn * 64 + ni * 16 + col;
                    Cf[(size_t)gm * ldc + gn] = acc[mi][ni][r];
                }
    } else {
        // repack 256x256 bf16 tile in LDS (stride 256, exactly 128 KiB,
        // bijective), then 512B-row vector stores. Last phase's barrier2
        // already separates all K-loop LDS reads from this overwrite.
        bf16* Cb = (bf16*)C;
#pragma unroll
        for (int mi = 0; mi < 8; mi++)
#pragma unroll
            for (int ni = 0; ni < 4; ni++)
#pragma unroll
                for (int r = 0; r < 4; r++) {
                    float v = acc[mi][ni][r];
                    if (MODE == 2) v = (v > 0.f) ? (v + 1.f) : __expf(v);
                    smem[(wm * 128 + mi * 16 + row0 + r) * 256 +
                         wn * 64 + ni * 16 + col] = (bf16)v;
                }
        __syncthreads();
#pragma unroll
        for (int i = 0; i < 16; i++) {
            int c = t + i * 512;
            int row = c >> 5, cb = (c & 31) * 8;
            *(bf16x8*)&Cb[(size_t)(tileM + row) * ldc + tileN + cb] =
                *(const bf16x8*)&smem[row * 256 + cb];
        }
    }
}

// ---------------------------------------------------------------------------
// Phase 2: per (b,h): KvT[n][m] += sum_l Kf[l][m] V[l][n];  row 64 = K1
// ---------------------------------------------------------------------------
__global__ __launch_bounds__(256) void kv_reduce(const bf16* __restrict__ Kft,
                                                 const bf16* __restrict__ Vt,
                                                 float* __restrict__ Kv) {
    const int chunk = blockIdx.x; // 0..7
    const int bh = blockIdx.y;    // 0..63
    const int b = bh >> 4, h = bh & 15;
    __shared__ bf16 sA[64 * 32] __attribute__((aligned(16)));
    __shared__ bf16 sB[64 * 32] __attribute__((aligned(16)));
    const int t = threadIdx.x, wave = t >> 6, lane = t & 63;
    const size_t cbase = (size_t)b * 8192 + (size_t)chunk * 1024;
    const int srow = t >> 2, scol = (t & 3) * 8;
    const bf16* a0 = Kft + (size_t)(h * 64 + srow) * 32768 + cbase + scol;
    const bf16* b0 = Vt + (size_t)(h * 64 + srow) * 32768 + cbase + scol;
    bf16* dA = sA + wave * 512;
    bf16* dB = sB + wave * 512;
    const int rm = lane & 15, qk = (lane >> 4) * 8;

    f32x4 acc[4] = {};
    f32x4 acc1 = {0.f, 0.f, 0.f, 0.f};
    bf16x8 ones;
#pragma unroll
    for (int j = 0; j < 8; j++) ones[j] = (bf16)1.0f;

    for (int k0 = 0; k0 < 1024; k0 += 32) {
        lds16(a0 + k0, dA);
        lds16(b0 + k0, dB);
        __builtin_amdgcn_s_waitcnt(0);
        __syncthreads();
        bf16x8 af = *(const bf16x8*)&sA[(wave * 16 + rm) * 32 + qk];
        bf16x8 bfr[4];
#pragma unroll
        for (int ni = 0; ni < 4; ni++)
            bfr[ni] = *(const bf16x8*)&sB[(ni * 16 + rm) * 32 + qk];
#pragma unroll
        for (int ni = 0; ni < 4; ni++)
            acc[ni] = __builtin_amdgcn_mfma_f32_16x16x32_bf16(af, bfr[ni], acc[ni], 0, 0, 0);
        acc1 = __builtin_amdgcn_mfma_f32_16x16x32_bf16(af, ones, acc1, 0, 0, 0);
        __syncthreads();
    }

    float* out = Kv + bh * 65 * 64;
    const int row0 = (lane >> 4) * 4, col = lane & 15;
    const int m0 = wave * 16 + row0;
#pragma unroll
    for (int ni = 0; ni < 4; ni++)
#pragma unroll
        for (int r = 0; r < 4; r++)
            atomicAdd(&out[(ni * 16 + col) * 64 + m0 + r], acc[ni][r]);
    if (col == 0) {
#pragma unroll
        for (int r = 0; r < 4; r++) atomicAdd(&out[64 * 64 + m0 + r], acc1[r]);
    }
}

// ---------------------------------------------------------------------------
// Phase 3: attn = num/den, LDS-repacked vector epilogue.
// ---------------------------------------------------------------------------
__global__ __launch_bounds__(256) void attn_out(const bf16* __restrict__ Qf,
                                                const float* __restrict__ Kv,
                                                bf16* __restrict__ attn) {
    const int lt = blockIdx.x; // 0..63
    const int bh = blockIdx.y; // 0..63
    const int b = bh >> 4, h = bh & 15;
    constexpr int EP_STRIDE = 80;
    __shared__ bf16 smem[13312] __attribute__((aligned(16)));
    __shared__ float den[128];
    bf16* sQ = smem;
    bf16* sB = smem + 8192;
    const int t = threadIdx.x, wave = t >> 6, lane = t & 63;
    const int qrow = t >> 3, qc = (t & 7) * 8;
    const bf16* qp = Qf + (size_t)(b * 8192 + lt * 128 + qrow) * 1024 + h * 64 + qc;
#pragma unroll
    for (int i = 0; i < 4; i++)
        lds16(qp + (size_t)i * 32 * 1024, sQ + i * 2048 + wave * 512);
    const float* kv = Kv + bh * 65 * 64;
    for (int idx = t; idx < 80 * 64; idx += 256) {
        int n = idx >> 6, k2 = idx & 63;
        sB[idx] = (n < 65) ? (bf16)kv[n * 64 + k2] : (bf16)0.f;
    }
    __builtin_amdgcn_s_waitcnt(0);
    __syncthreads();

    f32x4 acc[2][5] = {};
    const int rm = lane & 15, qk = (lane >> 4) * 8;
#pragma unroll
    for (int k0 = 0; k0 < 64; k0 += 32) {
        bf16x8 af[2], bfr[5];
#pragma unroll
        for (int mi = 0; mi < 2; mi++)
            af[mi] = *(const bf16x8*)&sQ[(wave * 32 + mi * 16 + rm) * 64 + k0 + qk];
#pragma unroll
        for (int ni = 0; ni < 5; ni++)
            bfr[ni] = *(const bf16x8*)&sB[(ni * 16 + rm) * 64 + k0 + qk];
#pragma unroll
        for (int mi = 0; mi < 2; mi++)
#pragma unroll
            for (int ni = 0; ni < 5; ni++)
                acc[mi][ni] = __builtin_amdgcn_mfma_f32_16x16x32_bf16(
                    af[mi], bfr[ni], acc[mi][ni], 0, 0, 0);
    }

    const int row0 = (lane >> 4) * 4, col = lane & 15;
    if (col == 0) {
#pragma unroll
        for (int mi = 0; mi < 2; mi++)
#pragma unroll
            for (int r = 0; r < 4; r++)
                den[wave * 32 + mi * 16 + row0 + r] = acc[mi][4][r] + ATT_EPS;
    }
    __syncthreads();
#pragma unroll
    for (int mi = 0; mi < 2; mi++)
#pragma unroll
        for (int ni = 0; ni < 4; ni++)
#pragma unroll
            for (int r = 0; r < 4; r++) {
                int rl = wave * 32 + mi * 16 + row0 + r;
                smem[rl * EP_STRIDE + ni * 16 + col] =
                    (bf16)(acc[mi][ni][r] / den[rl]);
            }
    __syncthreads();
    const int er = t >> 3, ec = (t & 7) * 8;
#pragma unroll
    for (int i = 0; i < 4; i++) {
        int row = er + i * 32;
        *(bf16x8*)&attn[(size_t)(b * 8192 + lt * 128 + row) * 1024 + h * 64 + ec] =
            *(const bf16x8*)&smem[row * EP_STRIDE + ec];
    }
}

// ---------------------------------------------------------------------------
extern "C" void kernel_launch(void* const* d_in, const int* in_sizes, int n_in,
                              void* d_out, int out_size, void* d_ws, size_t ws_size,
                              hipStream_t stream) {
    const float* x  = (const float*)d_in[0];
    const float* Wq = (const float*)d_in[1];
    const float* Wk = (const float*)d_in[2];
    const float* Wv = (const float*)d_in[3];
    const float* Wo = (const float*)d_in[4];

    char* ws = (char*)d_ws;
    bf16* xb  = (bf16*)ws;                           // 64 MB, reused as attn
    bf16* Qf  = (bf16*)(ws + ((size_t)64 << 20));    // 64 MB
    bf16* Kft = (bf16*)(ws + ((size_t)128 << 20));   // 64 MB
    bf16* Vt  = (bf16*)(ws + ((size_t)192 << 20));   // 64 MB
    bf16* Wqt = (bf16*)(ws + ((size_t)256 << 20));   // 2 MB each
    bf16* Wkt = Wqt + 1024 * 1024;
    bf16* Wvt = Wkt + 1024 * 1024;
    bf16* Wot = Wvt + 1024 * 1024;
    float* Kv = (float*)(Wot + 1024 * 1024);         // 64*65*64 fp32
    bf16* attn = xb;

    cvt_bf16<<<8388608 / 256, 256, 0, stream>>>((const float4*)x, (bf16x4*)xb, 8388608);
    dim3 tb(32, 8);
    transpose_w<<<dim3(32, 32), tb, 0, stream>>>(Wq, Wqt);
    transpose_w<<<dim3(32, 32), tb, 0, stream>>>(Wk, Wkt);
    transpose_w<<<dim3(32, 32), tb, 0, stream>>>(Wv, Wvt);
    transpose_w<<<dim3(32, 32), tb, 0, stream>>>(Wo, Wot);
    hipMemsetAsync(Kv, 0, (size_t)64 * 65 * 64 * sizeof(float), stream);

    // Qf = phi(x @ Wq): 128 m-tiles x 4 n-tiles, N fast (fl2=2)
    gemm8p<2><<<512, 512, 0, stream>>>(xb, 1024, Wqt, 1024, Qf, 1024, 1024, 0, 2);
    // Kft = phi(Wk^T x^T): 4 m-tiles x 128 n-tiles, M fast (fl2=2)
    gemm8p<2><<<512, 512, 0, stream>>>(Wkt, 1024, xb, 1024, Kft, 32768, 1024, 1, 2);
    // Vt = Wv^T x^T
    gemm8p<1><<<512, 512, 0, stream>>>(Wvt, 1024, xb, 1024, Vt, 32768, 1024, 1, 2);
    // KvT (+K1 row) per (b,h), 8 l-chunks
    kv_reduce<<<dim3(8, 64), 256, 0, stream>>>(Kft, Vt, Kv);
    // attn = num/den (into xb)
    attn_out<<<dim3(64, 64), 256, 0, stream>>>(Qf, Kv, attn);
    // out = attn @ Wo (fp32), N fast
    gemm8p<0><<<512, 512, 0, stream>>>(attn, 1024, Wot, 1024, d_out, 1024, 1024, 0, 2);
}